// Round 13
// baseline (926.861 us; speedup 1.0000x reference)
//
#include <hip/hip_runtime.h>

#define HID 64
#define TSTEPS 1024
#define BPW 8            // batch elements per workgroup (fixed by MFMA N=16 hi/lo)
#define TW 512           // 8 uniform waves, two-phase schedule (R7 base)

typedef __attribute__((ext_vector_type(8))) short short8v;   // 8 bf16
typedef __attribute__((ext_vector_type(4))) float f32x4;

__device__ __forceinline__ unsigned short f2bf(float f) {
  unsigned u = __float_as_uint(f);
  u += 0x7FFFu + ((u >> 16) & 1u);
  return (unsigned short)(u >> 16);
}
__device__ __forceinline__ float bf2f(unsigned short h) {
  return __uint_as_float(((unsigned)h) << 16);
}
__device__ __forceinline__ float sigf(float x) {
  return __builtin_amdgcn_rcpf(1.0f + __expf(-x));
}
__device__ __forceinline__ float tanh_(float x) {
  return 1.0f - 2.0f * __builtin_amdgcn_rcpf(1.0f + __expf(2.0f * x));
}
// value from lane^8 within each 16-lane row (row_ror:8, pure VALU)
__device__ __forceinline__ float dppror8(float x) {
  int xi = __float_as_int(x);
  int y = __builtin_amdgcn_update_dpp(xi, xi, 0x128, 0xF, 0xF, true);
  return __int_as_float(y);
}
__device__ __forceinline__ f32x4 mf(short8v a, short8v b, f32x4 c) {
  return __builtin_amdgcn_mfma_f32_16x16x32_bf16(a, b, c, 0, 0, 0);
}
// single-instruction f32->bf16 RTNE (both halves = bf16(a); we use low 16)
__device__ __forceinline__ unsigned cvtpk_bf16(float a) {
  unsigned r;
  asm("v_cvt_pk_bf16_f32 %0, %1, %2" : "=v"(r) : "v"(a), "v"(a));
  return r;
}
// byte offset (swizzled) of the lane's B-fragment half `ss` in a frag buffer
__device__ __forceinline__ int frag_ld_off(int ss, int lane) {
  int byte = (ss * 64 + lane) * 16;
  byte ^= ((byte >> 7) & 7) << 4;
  return byte;
}
// byte offset of element B[k=j][n=col] in the frag buffer (same swizzle)
__device__ __forceinline__ int frag_addr16(int j, int col) {
  int byte = ((j >> 5) * 64 + ((j & 31) >> 3) * 16 + col) * 16 + (j & 7) * 2;
  byte ^= ((byte >> 7) & 7) << 4;
  return byte;
}
// load 8 consecutive f32, split into bf16 hi/lo fragments (prologue only)
__device__ __forceinline__ void load8split(const float* rp, short8v& hi, short8v& lo) {
  float t[8];
#pragma unroll
  for (int e = 0; e < 8; ++e) t[e] = rp[e];
#pragma unroll
  for (int e = 0; e < 8; ++e) {
    unsigned short h = f2bf(t[e]);
    hi[e] = (short)h;
    lo[e] = (short)f2bf(t[e] - bf2f(h));
  }
}
__device__ __forceinline__ float cellup(float zi, float zf, float zg, float zo,
                                        float& c) {
  c = sigf(zf) * c + sigf(zi) * tanh_(zg);
  return sigf(zo) * tanh_(c);
}
// fold hi/lo column halves: lane keeps tile (d? 1:0), z = own + partner's half
__device__ __forceinline__ void fold2(const f32x4& a0, const f32x4& a1,
                                      bool dsel, float (&z)[4]) {
#pragma unroll
  for (int q = 0; q < 4; ++q) {
    float send = dsel ? a0[q] : a1[q];
    float own = dsel ? a1[q] : a0[q];
    z[q] = own + dppror8(send);
  }
}

struct __align__(128) SMem {
  float xin[TSTEPS + 1][BPW];   // transposed input; slot TSTEPS = future x
  short hf1[2][1024];           // h1 B-frags (hi cols 0-7, lo cols 8-15), swizzled
  short hf2[2][1024];           // h2 B-frags
  float ro[8][BPW];             // readout partials
};

// In-LOOP VGPR pin: forces the fragments to be arch-VGPR-resident every
// iteration, so the allocator's cheapest option is keeping them in VGPRs
// permanently (R12 analysis: prologue-only pins let it park weights in AGPRs
// and emit ~96 v_accvgpr shuttles per wave per step).
#define PIN6(a, b, c, d, e, f)                                              \
  asm volatile("" : "+v"(a), "+v"(b), "+v"(c), "+v"(d), "+v"(e), "+v"(f))

__global__ __launch_bounds__(TW, 2) void lstm2_kernel(
    const float* __restrict__ input, const float* __restrict__ Wih1,
    const float* __restrict__ Whh1, const float* __restrict__ bih1,
    const float* __restrict__ bhh1, const float* __restrict__ Wih2,
    const float* __restrict__ Whh2, const float* __restrict__ bih2,
    const float* __restrict__ bhh2, const float* __restrict__ Wl,
    const float* __restrict__ bl, const int* __restrict__ future,
    float* __restrict__ out) {
  __shared__ SMem s;
  const int tid = threadIdx.x;
  const int w = tid >> 6;
  const int lane = tid & 63;
  const int c = lane & 15;         // C col
  const int b = c & 7;             // batch
  const int d = (c >> 3) & 1;      // tile-select bit
  const int g = lane >> 4;         // row group -> j offset within tile
  const int jl = 4 * (2 * w + d) + g;  // lane's owned hidden index (both layers)
  const int b0 = blockIdx.x * BPW;

  // ---- weight fragments (A-operand). Tile T covers j in [4T,4T+4),
  // rows interleaved so C reg q = gate q for cell (b, j=4T+g):
  //   m(r16) = 64*(r16&3) + 4*T + (r16>>2)
  short8v W1h[2][2], W1l[2][2];  // Whh1  [tile][K-half]
  short8v W2h[2][2], W2l[2][2];  // Wih2
  short8v W3h[2][2], W3l[2][2];  // Whh2
#pragma unroll
  for (int tt = 0; tt < 2; ++tt) {
    const int T = 2 * w + tt;
    const int r16 = lane & 15;
    const int m = 64 * (r16 & 3) + 4 * T + (r16 >> 2);
    const int koff = (lane >> 4) * 8;
#pragma unroll
    for (int ss = 0; ss < 2; ++ss) {
      load8split(Whh1 + m * HID + ss * 32 + koff, W1h[tt][ss], W1l[tt][ss]);
      load8split(Wih2 + m * HID + ss * 32 + koff, W2h[tt][ss], W2l[tt][ss]);
      load8split(Whh2 + m * HID + ss * 32 + koff, W3h[tt][ss], W3l[tt][ss]);
    }
  }

  // ---- per-lane biases / vectors for cells (b, jl) of both layers ----
  float bb1[4], wi1[4], bb2[4];
#pragma unroll
  for (int q = 0; q < 4; ++q) {
    const int row = 64 * q + jl;
    bb1[q] = bih1[row] + bhh1[row];
    wi1[q] = Wih1[row];
    bb2[q] = bih2[row] + bhh2[row];
  }
  const float wlv = Wl[jl];
  const float blv = bl[0];
  const int nfut = future[0];
  const int adr_hi = frag_addr16(jl, b);      // hi half -> col b
  const int adr_lo = frag_addr16(jl, b + 8);  // lo half -> col b+8
  const int off0 = frag_ld_off(0, lane);      // hoisted read offsets
  const int off1 = frag_ld_off(1, lane);

  // ---- stage input (transposed) + zero frag buffers ----
  {
    const float* src = input + (size_t)b0 * TSTEPS;  // F==1, [B][T]
    for (int idx = tid; idx < BPW * TSTEPS; idx += TW) {
      int bi = idx >> 10;
      int t = idx & (TSTEPS - 1);
      s.xin[t][bi] = src[idx];
    }
    for (int idx = tid; idx < 2 * 1024; idx += TW) {
      ((short*)s.hf1)[idx] = 0;
      ((short*)s.hf2)[idx] = 0;
    }
  }
  const f32x4 zf = (f32x4){0.f, 0.f, 0.f, 0.f};
  f32x4 acc1_0 = zf, acc1_1 = zf;  // Whh1 @ h1 (pipelined from phase C)
  f32x4 acc2_0 = zf, acc2_1 = zf;  // Whh2 @ h2 then + Wih2 @ h1
  float c1 = 0.f, c2 = 0.f;
  float h2n = 0.f;
  __syncthreads();

  const int total = TSTEPS + nfut;
  for (int sidx = 0; sidx < total; ++sidx) {
    const int p = sidx & 1, pn = p ^ 1;

    // keep all 24 weight fragments arch-VGPR-resident through the iteration
    PIN6(W1h[0][0], W1h[0][1], W1h[1][0], W1h[1][1], W1l[0][0], W1l[0][1]);
    PIN6(W1l[1][0], W1l[1][1], W2h[0][0], W2h[0][1], W2h[1][0], W2h[1][1]);
    PIN6(W2l[0][0], W2l[0][1], W2l[1][0], W2l[1][1], W3h[0][0], W3h[0][1]);
    PIN6(W3h[1][0], W3h[1][1], W3l[0][0], W3l[0][1], W3l[1][0], W3l[1][1]);

    // ================= phase A =================
    // 1) issue MFMA first: acc2 = Whh2 @ h2(t-1)  (independent of gates1)
    {
      const char* hb = (const char*)s.hf2[p];
      short8v B0 = *(const short8v*)(hb + off0);
      short8v B1 = *(const short8v*)(hb + off1);
      acc2_0 = mf(W3h[0][1], B1,
                  mf(W3l[0][1], B1, mf(W3h[0][0], B0, mf(W3l[0][0], B0, zf))));
      acc2_1 = mf(W3h[1][1], B1,
                  mf(W3l[1][1], B1, mf(W3h[1][0], B0, mf(W3l[1][0], B0, zf))));
    }
    // 2) gates1 (depends only on acc1 from last phase C) overlaps the drain
    {
      const int xt = (sidx < TSTEPS) ? sidx : TSTEPS;
      const float xv = s.xin[xt][b];
      float z[4];
      fold2(acc1_0, acc1_1, d, z);
#pragma unroll
      for (int q = 0; q < 4; ++q) z[q] += bb1[q] + xv * wi1[q];
      float h1n = cellup(z[0], z[1], z[2], z[3], c1);
      unsigned rh = cvtpk_bf16(h1n);
      float res = h1n - __uint_as_float(rh << 16);
      unsigned rl = cvtpk_bf16(res);
      char* hf1w = (char*)s.hf1[pn];
      *(short*)(hf1w + adr_hi) = (short)rh;
      *(short*)(hf1w + adr_lo) = (short)rl;
    }
    __syncthreads();

    // ================= phase C =================
    {
      const char* cb = (const char*)s.hf1[pn];
      short8v C0 = *(const short8v*)(cb + off0);
      short8v C1 = *(const short8v*)(cb + off1);
      // gates2-feeding chains first:
      acc2_0 = mf(W2h[0][1], C1,
                  mf(W2l[0][1], C1, mf(W2h[0][0], C0, mf(W2l[0][0], C0, acc2_0))));
      acc2_1 = mf(W2h[1][1], C1,
                  mf(W2l[1][1], C1, mf(W2h[1][0], C0, mf(W2l[1][0], C0, acc2_1))));
      // next-step chains drain under the gates2 VALU below:
      acc1_0 = mf(W1h[0][1], C1,
                  mf(W1l[0][1], C1, mf(W1h[0][0], C0, mf(W1l[0][0], C0, zf))));
      acc1_1 = mf(W1h[1][1], C1,
                  mf(W1l[1][1], C1, mf(W1h[1][0], C0, mf(W1l[1][0], C0, zf))));
      float z[4];
      fold2(acc2_0, acc2_1, d, z);
#pragma unroll
      for (int q = 0; q < 4; ++q) z[q] += bb2[q];
      h2n = cellup(z[0], z[1], z[2], z[3], c2);
      unsigned rh = cvtpk_bf16(h2n);
      float res = h2n - __uint_as_float(rh << 16);
      unsigned rl = cvtpk_bf16(res);
      char* hf2w = (char*)s.hf2[pn];
      *(short*)(hf2w + adr_hi) = (short)rh;
      *(short*)(hf2w + adr_lo) = (short)rl;
    }

    // ---- readout (last main step + every future step) ----
    if (sidx >= TSTEPS - 1) {
      float v = wlv * h2n;
      v += __shfl_xor(v, 8, 64);
      v += __shfl_xor(v, 16, 64);
      v += __shfl_xor(v, 32, 64);
      if (lane < 8) s.ro[w][lane] = v;
      __syncthreads();
      if (tid < 8) {
        float t = blv;
#pragma unroll
        for (int k = 0; k < 8; ++k) t += s.ro[k][tid];
        s.xin[TSTEPS][tid] = t;
      }
    }
    __syncthreads();
  }

  if (tid < 8) out[b0 + tid] = s.xin[TSTEPS][tid];
}

extern "C" void kernel_launch(void* const* d_in, const int* in_sizes, int n_in,
                              void* d_out, int out_size, void* d_ws,
                              size_t ws_size, hipStream_t stream) {
  const float* input = (const float*)d_in[0];
  const float* Wih1 = (const float*)d_in[1];
  const float* Whh1 = (const float*)d_in[2];
  const float* bih1 = (const float*)d_in[3];
  const float* bhh1 = (const float*)d_in[4];
  const float* Wih2 = (const float*)d_in[5];
  const float* Whh2 = (const float*)d_in[6];
  const float* bih2 = (const float*)d_in[7];
  const float* bhh2 = (const float*)d_in[8];
  const float* Wl = (const float*)d_in[9];
  const float* bl = (const float*)d_in[10];
  const int* fut = (const int*)d_in[11];
  float* out = (float*)d_out;

  const int B = in_sizes[0] / TSTEPS;  // F == 1
  const int blocks = B / BPW;          // 256 (one per CU)

  hipLaunchKernelGGL(lstm2_kernel, dim3(blocks), dim3(TW), 0, stream, input,
                     Wih1, Whh1, bih1, bhh1, Wih2, Whh2, bih2, bhh2, Wl, bl,
                     fut, out);
}

// Round 14
// 858.800 us; speedup vs baseline: 1.0793x; 1.0793x over previous
//
#include <hip/hip_runtime.h>

#define HID 64
#define TSTEPS 1024
#define BPW 8            // batch elements per workgroup (fixed by MFMA N=16 hi/lo)
#define TW 1024          // 16 waves: 0-7 layer-1 group, 8-15 layer-2 group

typedef __attribute__((ext_vector_type(8))) short short8v;   // 8 bf16
typedef __attribute__((ext_vector_type(4))) float f32x4;

__device__ __forceinline__ unsigned short f2bf(float f) {
  unsigned u = __float_as_uint(f);
  u += 0x7FFFu + ((u >> 16) & 1u);
  return (unsigned short)(u >> 16);
}
__device__ __forceinline__ float bf2f(unsigned short h) {
  return __uint_as_float(((unsigned)h) << 16);
}
__device__ __forceinline__ float sigf(float x) {
  return __builtin_amdgcn_rcpf(1.0f + __expf(-x));
}
__device__ __forceinline__ float tanh_(float x) {
  return 1.0f - 2.0f * __builtin_amdgcn_rcpf(1.0f + __expf(2.0f * x));
}
// value from lane^8 within each 16-lane row (row_ror:8, pure VALU)
__device__ __forceinline__ float dppror8(float x) {
  int xi = __float_as_int(x);
  int y = __builtin_amdgcn_update_dpp(xi, xi, 0x128, 0xF, 0xF, true);
  return __int_as_float(y);
}
__device__ __forceinline__ f32x4 mf(short8v a, short8v b, f32x4 c) {
  return __builtin_amdgcn_mfma_f32_16x16x32_bf16(a, b, c, 0, 0, 0);
}
__device__ __forceinline__ unsigned cvtpk_bf16(float a) {
  unsigned r;
  asm("v_cvt_pk_bf16_f32 %0, %1, %2" : "=v"(r) : "v"(a), "v"(a));
  return r;
}
__device__ __forceinline__ int frag_ld_off(int ss, int lane) {
  int byte = (ss * 64 + lane) * 16;
  byte ^= ((byte >> 7) & 7) << 4;
  return byte;
}
__device__ __forceinline__ int frag_addr16(int j, int col) {
  int byte = ((j >> 5) * 64 + ((j & 31) >> 3) * 16 + col) * 16 + (j & 7) * 2;
  byte ^= ((byte >> 7) & 7) << 4;
  return byte;
}
__device__ __forceinline__ void load8split(const float* rp, short8v& hi, short8v& lo) {
  float t[8];
#pragma unroll
  for (int e = 0; e < 8; ++e) t[e] = rp[e];
#pragma unroll
  for (int e = 0; e < 8; ++e) {
    unsigned short h = f2bf(t[e]);
    hi[e] = (short)h;
    lo[e] = (short)f2bf(t[e] - bf2f(h));
  }
}
__device__ __forceinline__ float cellup(float zi, float zf, float zg, float zo,
                                        float& c) {
  c = sigf(zf) * c + sigf(zi) * tanh_(zg);
  return sigf(zo) * tanh_(c);
}
// fold hi/lo column halves: lane keeps tile (d?1:0), z = own + partner's half
__device__ __forceinline__ void fold2(const f32x4& a0, const f32x4& a1,
                                      bool dsel, float (&z)[4]) {
#pragma unroll
  for (int q = 0; q < 4; ++q) {
    float send = dsel ? a0[q] : a1[q];
    float own = dsel ? a1[q] : a0[q];
    z[q] = own + dppror8(send);
  }
}

// ---- workgroup-scope sync primitives (LDS counters, no __syncthreads) ----
__device__ __forceinline__ void spin_ge(int* p, int tgt) {
  if (__hip_atomic_load(p, __ATOMIC_ACQUIRE, __HIP_MEMORY_SCOPE_WORKGROUP) < tgt) {
    while (__hip_atomic_load(p, __ATOMIC_ACQUIRE,
                             __HIP_MEMORY_SCOPE_WORKGROUP) < tgt)
      __builtin_amdgcn_s_sleep(1);
  }
  __builtin_amdgcn_sched_barrier(0);
}
__device__ __forceinline__ void bump(int* p, int lane) {
  asm volatile("s_waitcnt lgkmcnt(0)" ::: "memory");  // frag stores visible first
  if (lane == 0)
    __hip_atomic_fetch_add(p, 1, __ATOMIC_RELEASE, __HIP_MEMORY_SCOPE_WORKGROUP);
}

struct __align__(128) SMem {
  float xin[TSTEPS][BPW];       // transposed input (32 KB)
  short hf1[4][1024];           // h1 B-frag ring, depth 4 (slot -1 = 3, zeroed)
  short hf2[2][1024];           // h2 B-frag ping-pong (slot -1 = 1, zeroed)
  float xfut[16][BPW];          // future-step x values
  float ro[2][8][BPW];          // readout partials, parity by step
  int h1_done, h2_done, x_ready;
};

__global__ __launch_bounds__(TW, 4) void lstm2_kernel(
    const float* __restrict__ input, const float* __restrict__ Wih1,
    const float* __restrict__ Whh1, const float* __restrict__ bih1,
    const float* __restrict__ bhh1, const float* __restrict__ Wih2,
    const float* __restrict__ Whh2, const float* __restrict__ bih2,
    const float* __restrict__ bhh2, const float* __restrict__ Wl,
    const float* __restrict__ bl, const int* __restrict__ future,
    float* __restrict__ out) {
  __shared__ SMem s;
  const int tid = threadIdx.x;
  const int w = tid >> 6;
  const int lane = tid & 63;
  const int gid = w >> 3;          // 0: layer-1 group, 1: layer-2 group
  const int v = w & 7;             // wave index within group -> tiles 2v, 2v+1
  const int c = lane & 15;
  const int b = c & 7;             // batch
  const int d = (c >> 3) & 1;      // tile-select bit
  const int g = lane >> 4;
  const int jl = 4 * (2 * v + d) + g;  // lane's owned hidden index
  const int b0 = blockIdx.x * BPW;
  const int nfut = future[0];
  const int total = TSTEPS + nfut;
  const float blv = bl[0];
  const int adr_hi = frag_addr16(jl, b);
  const int adr_lo = frag_addr16(jl, b + 8);
  const int off0 = frag_ld_off(0, lane);
  const int off1 = frag_ld_off(1, lane);
  const f32x4 zf = (f32x4){0.f, 0.f, 0.f, 0.f};

  // ---- stage input (transposed), zero frag buffers + counters ----
  {
    const float* src = input + (size_t)b0 * TSTEPS;  // F==1, [B][T]
    for (int idx = tid; idx < BPW * TSTEPS; idx += TW) {
      int bi = idx >> 10;
      int t = idx & (TSTEPS - 1);
      s.xin[t][bi] = src[idx];
    }
    for (int idx = tid; idx < 4 * 1024; idx += TW) ((short*)s.hf1)[idx] = 0;
    for (int idx = tid; idx < 2 * 1024; idx += TW) ((short*)s.hf2)[idx] = 0;
    if (tid == 0) {
      s.h1_done = 0;
      s.h2_done = 0;
      s.x_ready = 0;
    }
  }
  __syncthreads();  // the ONLY block-wide barrier

  if (gid == 0) {
    // ================= layer-1 group: h1(i) = LSTM1(x(i), h1(i-1)) ========
    short8v Ah[2][2], Al[2][2];  // Whh1 [tile][K-half]
#pragma unroll
    for (int tt = 0; tt < 2; ++tt) {
      const int T = 2 * v + tt;
      const int r16 = lane & 15;
      const int m = 64 * (r16 & 3) + 4 * T + (r16 >> 2);
      const int koff = (lane >> 4) * 8;
#pragma unroll
      for (int ss = 0; ss < 2; ++ss)
        load8split(Whh1 + m * HID + ss * 32 + koff, Ah[tt][ss], Al[tt][ss]);
    }
    float bb1[4], wi1[4];
#pragma unroll
    for (int q = 0; q < 4; ++q) {
      const int row = 64 * q + jl;
      bb1[q] = bih1[row] + bhh1[row];
      wi1[q] = Wih1[row];
    }
    float c1 = 0.f;
    for (int i = 0; i < total; ++i) {
      spin_ge(&s.h1_done, 8 * i);                     // peers done step i-1
      if (i >= 4) spin_ge(&s.h2_done, 8 * (i - 3));   // ring slot i&3 free
      const char* cb = (const char*)s.hf1[(i - 1) & 3];
      short8v C0 = *(const short8v*)(cb + off0);
      short8v C1 = *(const short8v*)(cb + off1);
      f32x4 a0 = mf(Ah[0][1], C1,
                    mf(Al[0][1], C1, mf(Ah[0][0], C0, mf(Al[0][0], C0, zf))));
      f32x4 a1 = mf(Ah[1][1], C1,
                    mf(Al[1][1], C1, mf(Ah[1][0], C0, mf(Al[1][0], C0, zf))));
      float x;
      if (i < TSTEPS) {
        x = s.xin[i][b];
      } else {
        spin_ge(&s.x_ready, i - TSTEPS + 1);
        x = s.xfut[i - TSTEPS][b];
      }
      float z[4];
      fold2(a0, a1, d, z);
#pragma unroll
      for (int q = 0; q < 4; ++q) z[q] += bb1[q] + x * wi1[q];
      float h1n = cellup(z[0], z[1], z[2], z[3], c1);
      unsigned rh = cvtpk_bf16(h1n);
      float res = h1n - __uint_as_float(rh << 16);
      unsigned rl = cvtpk_bf16(res);
      char* hw = (char*)s.hf1[i & 3];
      *(short*)(hw + adr_hi) = (short)rh;
      *(short*)(hw + adr_lo) = (short)rl;
      bump(&s.h1_done, lane);
    }
  } else {
    // ===== layer-2 group: h2(j) = LSTM2(h1(j), h2(j-1)); readout tail =====
    short8v Ah[2][2], Al[2][2];  // Wih2
    short8v Bh[2][2], Bl[2][2];  // Whh2
#pragma unroll
    for (int tt = 0; tt < 2; ++tt) {
      const int T = 2 * v + tt;
      const int r16 = lane & 15;
      const int m = 64 * (r16 & 3) + 4 * T + (r16 >> 2);
      const int koff = (lane >> 4) * 8;
#pragma unroll
      for (int ss = 0; ss < 2; ++ss) {
        load8split(Wih2 + m * HID + ss * 32 + koff, Ah[tt][ss], Al[tt][ss]);
        load8split(Whh2 + m * HID + ss * 32 + koff, Bh[tt][ss], Bl[tt][ss]);
      }
    }
    float bb2[4];
#pragma unroll
    for (int q = 0; q < 4; ++q) {
      const int row = 64 * q + jl;
      bb2[q] = bih2[row] + bhh2[row];
    }
    const float wlv = Wl[jl];
    float c2 = 0.f;
    for (int j = 0; j < total; ++j) {
      spin_ge(&s.h2_done, 8 * j);          // peers done step j-1
      spin_ge(&s.h1_done, 8 * (j + 1));    // h1(j) available
      const char* cb = (const char*)s.hf1[j & 3];
      short8v C0 = *(const short8v*)(cb + off0);
      short8v C1 = *(const short8v*)(cb + off1);
      const char* db = (const char*)s.hf2[(j - 1) & 1];
      short8v D0 = *(const short8v*)(db + off0);
      short8v D1 = *(const short8v*)(db + off1);
      // z2 = Wih2@h1(j) + Whh2@h2(j-1): one 8-deep chain per tile
      f32x4 a0 = mf(
          Bh[0][1], D1,
          mf(Bl[0][1], D1,
             mf(Bh[0][0], D0,
                mf(Bl[0][0], D0,
                   mf(Ah[0][1], C1,
                      mf(Al[0][1], C1,
                         mf(Ah[0][0], C0, mf(Al[0][0], C0, zf))))))));
      f32x4 a1 = mf(
          Bh[1][1], D1,
          mf(Bl[1][1], D1,
             mf(Bh[1][0], D0,
                mf(Bl[1][0], D0,
                   mf(Ah[1][1], C1,
                      mf(Al[1][1], C1,
                         mf(Ah[1][0], C0, mf(Al[1][0], C0, zf))))))));
      float z[4];
      fold2(a0, a1, d, z);
#pragma unroll
      for (int q = 0; q < 4; ++q) z[q] += bb2[q];
      float h2n = cellup(z[0], z[1], z[2], z[3], c2);
      unsigned rh = cvtpk_bf16(h2n);
      float res = h2n - __uint_as_float(rh << 16);
      unsigned rl = cvtpk_bf16(res);
      char* hw = (char*)s.hf2[j & 1];
      *(short*)(hw + adr_hi) = (short)rh;
      *(short*)(hw + adr_lo) = (short)rl;
      if (j >= TSTEPS - 1) {  // readout partial for out/future-x
        float rv = wlv * h2n;
        rv += __shfl_xor(rv, 8, 64);
        rv += __shfl_xor(rv, 16, 64);
        rv += __shfl_xor(rv, 32, 64);
        if (lane < 8) s.ro[j & 1][v][lane] = rv;
      }
      bump(&s.h2_done, lane);
      if (v == 0 && j >= TSTEPS - 1) {
        spin_ge(&s.h2_done, 8 * (j + 1));  // all peers' ro written
        float t = blv;
        if (lane < 8) {
#pragma unroll
          for (int k = 0; k < 8; ++k) t += s.ro[j & 1][k][lane];
        }
        if (j == total - 1) {
          if (lane < 8) out[b0 + lane] = t;
        } else {
          if (lane < 8) s.xfut[j - (TSTEPS - 1)][lane] = t;
          bump(&s.x_ready, lane);
        }
      }
    }
  }
}

extern "C" void kernel_launch(void* const* d_in, const int* in_sizes, int n_in,
                              void* d_out, int out_size, void* d_ws,
                              size_t ws_size, hipStream_t stream) {
  const float* input = (const float*)d_in[0];
  const float* Wih1 = (const float*)d_in[1];
  const float* Whh1 = (const float*)d_in[2];
  const float* bih1 = (const float*)d_in[3];
  const float* bhh1 = (const float*)d_in[4];
  const float* Wih2 = (const float*)d_in[5];
  const float* Whh2 = (const float*)d_in[6];
  const float* bih2 = (const float*)d_in[7];
  const float* bhh2 = (const float*)d_in[8];
  const float* Wl = (const float*)d_in[9];
  const float* bl = (const float*)d_in[10];
  const int* fut = (const int*)d_in[11];
  float* out = (float*)d_out;

  const int B = in_sizes[0] / TSTEPS;  // F == 1
  const int blocks = B / BPW;          // 256 (one per CU)

  hipLaunchKernelGGL(lstm2_kernel, dim3(blocks), dim3(TW), 0, stream, input,
                     Wih1, Whh1, bih1, bhh1, Wih2, Whh2, bih2, bhh2, Wl, bl,
                     fut, out);
}